// Round 3
// baseline (389.988 us; speedup 1.0000x reference)
//
#include <hip/hip_runtime.h>
#include <stdint.h>

typedef unsigned short u16;
typedef __attribute__((ext_vector_type(8))) short short8;
typedef __attribute__((ext_vector_type(4))) float f32x4;
typedef __attribute__((ext_vector_type(4))) unsigned short u16x4;

#define TOKENS 4096
#define E_DIM 1024
#define F_DIM 4096
#define SEQ 2048
#define NH 16
#define DH 64

__device__ __forceinline__ u16 f2b(float f) {
  union { float f; unsigned u; } v; v.f = f;
  unsigned r = v.u + 0x7fffu + ((v.u >> 16) & 1u);
  return (u16)(r >> 16);
}

__device__ __forceinline__ void gl2lds16(const u16* g, u16* l) {
  __builtin_amdgcn_global_load_lds(
      (const __attribute__((address_space(1))) unsigned int*)(size_t)(g),
      (__attribute__((address_space(3))) unsigned int*)(unsigned int)(size_t)(l),
      16, 0, 0);
}

// ---------------------------------------------------------------------------
__global__ __launch_bounds__(256)
void transpose_w(const float* __restrict__ W, u16* __restrict__ Wt, int K, int N) {
  __shared__ float tile[32][33];
  const int kb = blockIdx.x * 32, nb = blockIdx.y * 32;
  const int tx = threadIdx.x & 31, ty = threadIdx.x >> 5;  // 32 x 8
#pragma unroll
  for (int i = 0; i < 32; i += 8)
    tile[ty + i][tx] = W[(size_t)(kb + ty + i) * N + nb + tx];
  __syncthreads();
#pragma unroll
  for (int i = 0; i < 32; i += 8)
    Wt[(size_t)(nb + ty + i) * K + kb + tx] = f2b(tile[tx][ty + i]);
}

// ---------------------------------------------------------------------------
__global__ __launch_bounds__(256)
void f32_to_bf16(const float* __restrict__ in, u16* __restrict__ out) {
  const int i = blockIdx.x * 256 + threadIdx.x;
  f32x4 f = ((const f32x4*)in)[i];
  u16x4 u;
#pragma unroll
  for (int j = 0; j < 4; j++) u[j] = f2b(f[j]);
  ((u16x4*)out)[i] = u;
}

// ---------------------------------------------------------------------------
// v (token-major bf16) -> vt [B][H][DH][SEQ], key dimension sigma-permuted
// within each 64-key window: position p holds key (p&3)*16 + (p>>2).
// ---------------------------------------------------------------------------
__global__ __launch_bounds__(256)
void transpose_v(const u16* __restrict__ vsrc, u16* __restrict__ vt) {
  __shared__ u16 tile[64][66];
  const int kb = blockIdx.x * 64;
  const int bh = blockIdx.y;
  const int b = bh >> 4, h = bh & 15;
  {
    const int d = threadIdx.x & 63, r = threadIdx.x >> 6;  // 64 x 4
#pragma unroll
    for (int i = 0; i < 64; i += 4)
      tile[r + i][d] = vsrc[(size_t)(b * SEQ + kb + r + i) * E_DIM + h * DH + d];
  }
  __syncthreads();
  {
    const int pos = threadIdx.x & 63;
    const int srck = (pos & 3) * 16 + (pos >> 2);  // sigma^{-1}(pos)
#pragma unroll
    for (int j = 0; j < 64; j += 4) {
      const int d = (threadIdx.x >> 6) + j;
      vt[(size_t)(bh * DH + d) * SEQ + kb + pos] = tile[srck][d];
    }
  }
}

// ---------------------------------------------------------------------------
// gemm256: 256x256 tile, BK=32, phased schedule with counted vmcnt.
// Round-2 change: frag-order staging. Lane l's GLOBAL source is
// (row l&15, k-chunk l>>4) of its subtile, so the linear global_load_lds
// write (base + lane*16B) puts the subtile in exactly the order the MFMA
// frag ds_read_b128 wants: frag addr = subtile + lane*16B -> fully linear,
// conflict-free (was l15*64B+g*16B, an 8-way conflicted stride pattern).
// ---------------------------------------------------------------------------
template <int RELU, int OUTBF>
__global__ __launch_bounds__(512)
void gemm256(const u16* __restrict__ A, const u16* __restrict__ Bt,
             const float* __restrict__ bias, void* __restrict__ Cout,
             int N, int K) {
  __shared__ __align__(16) u16 lds[3][2][8192];  // [buf][A/B][16 subtiles x 512]
  const int tid = threadIdx.x;
  const int lane = tid & 63, wave = tid >> 6;
  const int wm = wave >> 2, wn = wave & 3;  // 2 x 4 wave grid
  const int l15 = lane & 15, g = lane >> 4;

  const int bid = blockIdx.x;
  const int xcd = bid & 7, idx = bid >> 3;          // idx in 0..31
  const int mT = (xcd >> 2) * 8 + (idx >> 2);       // 0..15
  const int nT = (xcd & 3) * 4 + (idx & 3);         // 0..15
  const int mBlk = mT * 256, nBlk = nT * 256;

  const u16* Ab = A + (size_t)mBlk * K;
  const u16* Bb = Bt + (size_t)nBlk * K;

  // frag-order staging source (see header comment)
  const int fr = lane & 15;
  const int fc = (lane >> 4) * 8;
  const u16* sa0 = Ab + (size_t)(wave * 16 + fr) * K + fc;
  const u16* sa1 = Ab + (size_t)((8 + wave) * 16 + fr) * K + fc;
  const u16* sb0 = Bb + (size_t)(wave * 16 + fr) * K + fc;
  const u16* sb1 = Bb + (size_t)((8 + wave) * 16 + fr) * K + fc;

  f32x4 acc[8][4] = {};

  const int NT = K >> 5;  // K-tiles of 32

#define STAGE_A(buf, t)                                             \
  {                                                                 \
    gl2lds16(sa0 + (size_t)(t) * 32, &lds[buf][0][wave * 512 + lane * 8]);       \
    gl2lds16(sa1 + (size_t)(t) * 32, &lds[buf][0][(8 + wave) * 512 + lane * 8]); \
  }
#define STAGE_B(buf, t)                                             \
  {                                                                 \
    gl2lds16(sb0 + (size_t)(t) * 32, &lds[buf][1][wave * 512 + lane * 8]);       \
    gl2lds16(sb1 + (size_t)(t) * 32, &lds[buf][1][(8 + wave) * 512 + lane * 8]); \
  }

  STAGE_A(0, 0) STAGE_B(0, 0)
  STAGE_A(1, 1) STAGE_B(1, 1)
  asm volatile("s_waitcnt vmcnt(4)" ::: "memory");
  asm volatile("s_barrier" ::: "memory");

  int buf = 0, sbuf = 2;
  for (int t = 0; t < NT; ++t) {
    const u16* As_ = &lds[buf][0][wm * (8 * 512)];
    const u16* Bs_ = &lds[buf][1][wn * (4 * 512)];
    const int fo = lane * 8;  // frag-order: fully linear per wave

    short8 af[4], bfr[4];
    // ---- phase 1 ----
#pragma unroll
    for (int i = 0; i < 4; i++)
      af[i] = *(const short8*)(As_ + i * 512 + fo);
#pragma unroll
    for (int i = 0; i < 4; i++)
      bfr[i] = *(const short8*)(Bs_ + i * 512 + fo);
    if (t + 2 < NT) STAGE_A(sbuf, t + 2)
    asm volatile("s_barrier" ::: "memory");
    asm volatile("s_waitcnt lgkmcnt(0)" ::: "memory");
    __builtin_amdgcn_sched_barrier(0);
    __builtin_amdgcn_s_setprio(1);
#pragma unroll
    for (int mg = 0; mg < 4; mg++)
#pragma unroll
      for (int ng = 0; ng < 4; ng++)
        acc[mg][ng] = __builtin_amdgcn_mfma_f32_16x16x32_bf16(af[mg], bfr[ng],
                                                              acc[mg][ng], 0, 0, 0);
    __builtin_amdgcn_s_setprio(0);
    asm volatile("s_barrier" ::: "memory");

    // ---- phase 2 ----
#pragma unroll
    for (int i = 0; i < 4; i++)
      af[i] = *(const short8*)(As_ + (4 + i) * 512 + fo);
    if (t + 2 < NT) STAGE_B(sbuf, t + 2)
    asm volatile("s_barrier" ::: "memory");
    asm volatile("s_waitcnt lgkmcnt(0)" ::: "memory");
    __builtin_amdgcn_sched_barrier(0);
    __builtin_amdgcn_s_setprio(1);
#pragma unroll
    for (int mg = 0; mg < 4; mg++)
#pragma unroll
      for (int ng = 0; ng < 4; ng++)
        acc[4 + mg][ng] = __builtin_amdgcn_mfma_f32_16x16x32_bf16(af[mg], bfr[ng],
                                                                  acc[4 + mg][ng], 0, 0, 0);
    __builtin_amdgcn_s_setprio(0);
    if (t + 2 < NT) asm volatile("s_waitcnt vmcnt(4)" ::: "memory");
    else            asm volatile("s_waitcnt vmcnt(0)" ::: "memory");
    asm volatile("s_barrier" ::: "memory");

    buf = (buf == 2) ? 0 : buf + 1;
    sbuf = (sbuf == 2) ? 0 : sbuf + 1;
  }
#undef STAGE_A
#undef STAGE_B

  const int row0 = mBlk + wm * 128 + g * 4;
  const int col0 = nBlk + wn * 64 + l15;
#pragma unroll
  for (int ng = 0; ng < 4; ng++) {
    const int c = col0 + ng * 16;
    const float bv = bias[c];
#pragma unroll
    for (int mg = 0; mg < 8; mg++) {
#pragma unroll
      for (int r = 0; r < 4; r++) {
        float v = acc[mg][ng][r] + bv;
        if (RELU) v = fmaxf(v, 0.f);
        const size_t o = (size_t)(row0 + mg * 16 + r) * N + c;
        if (OUTBF) ((u16*)Cout)[o] = f2b(v);
        else       ((float*)Cout)[o] = v;
      }
    }
  }
}

// ---------------------------------------------------------------------------
// gemm_wide_sk: 256M x 128N tile, split-K 2, fp32 partials to
// Cout + kz*TOKENS*N (bias on kz==0). Replaces gemm_bt_sk for Wo and FF2
// (both M=4096, N=1024). Grid = 256 blocks exactly (16 mT x 8 nT x 2 kz),
// 512 threads = 8 waves in a 4M x 2N grid (per-wave 64x64, acc[4][4] --
// squarest LDS:MFMA ratio: 64 ds_read_b128 per K-step-block for 128 MFMA).
//   - 3-deep LDS ring (3 x 24KB = 72KB -> 2 blocks/CU, 4 waves/SIMD).
//   - ONE barrier per K-step; steady-state s_waitcnt vmcnt(3) (3 loads/
//     thread/K-step; tile t+2's loads stay in flight across the barrier).
//     Race freedom: readers of buf[(t+2)%3] ran at iter t-1 and completed
//     (their lgkmcnt(0)) before iter t-1's trailing barrier; stages into
//     that buf are issued after it. Loads for tile t are confirmed done by
//     every wave's own vmcnt at iter t-1's tail, before the barrier.
//   - frag-order staging (see gemm256) -> conflict-free frag ds_reads.
//   - XCD swizzle: each XCD owns (8 mT x 4 nT x 1 kz) -> A-slice 8MB +
//     B-slice 2MB per XCD (FF2), ~80MB ideal fetch vs 135MB measured.
// ---------------------------------------------------------------------------
__global__ __launch_bounds__(512)
void gemm_wide_sk(const u16* __restrict__ A, const u16* __restrict__ Bt,
                  const float* __restrict__ bias, float* __restrict__ Cout,
                  int N, int K) {
  __shared__ __align__(16) u16 lds[3][12288];  // [buf][ A 16x512 | B 8x512 ]
  const int tid = threadIdx.x;
  const int lane = tid & 63, wave = tid >> 6;
  const int wm = wave >> 1, wn = wave & 1;  // 4M x 2N wave grid
  const int l15 = lane & 15, g = lane >> 4;

  const int bid = blockIdx.x;
  const int xcd = bid & 7, idx = bid >> 3;            // idx 0..31
  const int kz = xcd & 1;
  const int nT = ((xcd >> 1) & 1) * 4 + (idx & 3);    // 0..7
  const int mT = (xcd >> 2) * 8 + (idx >> 2);         // 0..15
  const int mBlk = mT * 256, nBlk = nT * 128;
  const int Kh = K >> 1;

  const u16* Ab = A + (size_t)mBlk * K + (size_t)kz * Kh;
  const u16* Bb = Bt + (size_t)nBlk * K + (size_t)kz * Kh;

  // frag-order staging source
  const int fr = lane & 15;
  const int fc = (lane >> 4) * 8;
  const u16* sa0 = Ab + (size_t)(wave * 16 + fr) * K + fc;
  const u16* sa1 = Ab + (size_t)((8 + wave) * 16 + fr) * K + fc;
  const u16* sb0 = Bb + (size_t)(wave * 16 + fr) * K + fc;

  f32x4 acc[4][4] = {};
  const int NT = Kh >> 5;

#define WSTAGE(buf, t)                                                         \
  {                                                                            \
    gl2lds16(sa0 + (size_t)(t) * 32, &lds[buf][wave * 512 + lane * 8]);        \
    gl2lds16(sa1 + (size_t)(t) * 32, &lds[buf][(8 + wave) * 512 + lane * 8]);  \
    gl2lds16(sb0 + (size_t)(t) * 32, &lds[buf][8192 + wave * 512 + lane * 8]); \
  }

  WSTAGE(0, 0)
  WSTAGE(1, 1)
  asm volatile("s_waitcnt vmcnt(3)" ::: "memory");
  asm volatile("s_barrier" ::: "memory");

  int buf = 0, sbuf = 2;
  for (int t = 0; t < NT; ++t) {
    const u16* As_ = &lds[buf][wm * (4 * 512)];
    const u16* Bs_ = &lds[buf][8192 + wn * (4 * 512)];
    short8 af[4], bfr[4];
#pragma unroll
    for (int i = 0; i < 4; i++)
      af[i] = *(const short8*)(As_ + i * 512 + lane * 8);
#pragma unroll
    for (int i = 0; i < 4; i++)
      bfr[i] = *(const short8*)(Bs_ + i * 512 + lane * 8);
    if (t + 2 < NT) WSTAGE(sbuf, t + 2)
    asm volatile("s_waitcnt lgkmcnt(0)" ::: "memory");
    __builtin_amdgcn_sched_barrier(0);
    __builtin_amdgcn_s_setprio(1);
#pragma unroll
    for (int mi = 0; mi < 4; mi++)
#pragma unroll
      for (int ni = 0; ni < 4; ni++)
        acc[mi][ni] = __builtin_amdgcn_mfma_f32_16x16x32_bf16(af[mi], bfr[ni],
                                                              acc[mi][ni], 0, 0, 0);
    __builtin_amdgcn_s_setprio(0);
    if (t + 2 < NT) asm volatile("s_waitcnt vmcnt(3)" ::: "memory");
    else            asm volatile("s_waitcnt vmcnt(0)" ::: "memory");
    asm volatile("s_barrier" ::: "memory");
    buf = (buf == 2) ? 0 : buf + 1;
    sbuf = (sbuf == 2) ? 0 : sbuf + 1;
  }
#undef WSTAGE

  float* out = Cout + (size_t)kz * TOKENS * N;
  const int row0 = mBlk + wm * 64 + g * 4;
  const int col0 = nBlk + wn * 64 + l15;
#pragma unroll
  for (int ni = 0; ni < 4; ni++) {
    const int c = col0 + ni * 16;
    const float bv = (kz == 0) ? bias[c] : 0.f;
#pragma unroll
    for (int mi = 0; mi < 4; mi++) {
#pragma unroll
      for (int r = 0; r < 4; r++)
        out[(size_t)(row0 + mi * 16 + r) * N + c] = acc[mi][ni][r] + bv;
    }
  }
}

// ---------------------------------------------------------------------------
// Fused Q+V GEMM: Bqv = [WqT | WvT] contiguous (2048 x K). Q half scaled by
// (1/sqrt(Dh)) * log2(e) -- attention uses exp2 directly.
// Round-2: frag-order staging (conflict-free frag ds_reads).
// ---------------------------------------------------------------------------
__global__ __launch_bounds__(256)
void gemm_qv64(const u16* __restrict__ A, const u16* __restrict__ Bqv,
               const float* __restrict__ bq, const float* __restrict__ bv,
               u16* __restrict__ qout, u16* __restrict__ vout, int K) {
  __shared__ __align__(16) u16 As[128 * 32];
  __shared__ __align__(16) u16 Bs[64 * 32];
  const int tid = threadIdx.x;
  const int lane = tid & 63, wave = tid >> 6;
  const int mBlk = blockIdx.y * 128, nBlk = blockIdx.x * 64;
  const int isQ = nBlk < 1024;
  const int ncol = isQ ? nBlk : nBlk - 1024;
  const float* bias = isQ ? bq : bv;
  u16* out = isQ ? qout : vout;
  const float oscale = isQ ? 0.125f * 1.44269504088896f : 1.0f;
  const int wm = (wave >> 1) * 64, wn = (wave & 1) * 32;
  const int l15 = lane & 15, g = lane >> 4;

  f32x4 acc[4][2] = {};
  const int fr = lane & 15;
  const int fc = (lane >> 4) * 8;

  const u16* Ab = A + (size_t)mBlk * K;
  const u16* Bb = Bqv + (size_t)nBlk * K;

  for (int k0 = 0; k0 < K; k0 += 32) {
    __syncthreads();
    for (int c = wave; c < 8; c += 4)
      gl2lds16(Ab + (size_t)(c * 16 + fr) * K + k0 + fc, As + c * 512 + lane * 8);
    gl2lds16(Bb + (size_t)(wave * 16 + fr) * K + k0 + fc, Bs + wave * 512 + lane * 8);
    __syncthreads();

    short8 af[4], bf[2];
#pragma unroll
    for (int i = 0; i < 4; i++)
      af[i] = *(const short8*)(As + ((wm >> 4) + i) * 512 + lane * 8);
#pragma unroll
    for (int i = 0; i < 2; i++)
      bf[i] = *(const short8*)(Bs + ((wn >> 4) + i) * 512 + lane * 8);
#pragma unroll
    for (int mi = 0; mi < 4; mi++)
#pragma unroll
      for (int ni = 0; ni < 2; ni++)
        acc[mi][ni] = __builtin_amdgcn_mfma_f32_16x16x32_bf16(af[mi], bf[ni],
                                                              acc[mi][ni], 0, 0, 0);
  }

  const int row0 = mBlk + wm + g * 4;
  const int col0 = ncol + wn + l15;
#pragma unroll
  for (int ni = 0; ni < 2; ni++) {
    const int c = col0 + ni * 16;
    const float bv_ = bias[c];
#pragma unroll
    for (int mi = 0; mi < 4; mi++) {
#pragma unroll
      for (int r = 0; r < 4; r++) {
        float v = (acc[mi][ni][r] + bv_) * oscale;
        out[(size_t)(row0 + mi * 16 + r) * E_DIM + c] = f2b(v);
      }
    }
  }
}

// ---------------------------------------------------------------------------
// Flash attention v5 (round-1): 4 waves x 16 q-rows, double-buffered staging,
// raw s_barrier + counted vmcnt, exp2 direct. Unchanged this round.
// ---------------------------------------------------------------------------
__global__ __launch_bounds__(256)
void attn_kernel(const u16* __restrict__ qb, const u16* __restrict__ vb,
                 const u16* __restrict__ vtb, u16* __restrict__ ctxb) {
  __shared__ __align__(16) u16 Vs[2][64 * 64];   // [key][d-chunk ^ (key&7)]
  __shared__ __align__(16) u16 Vts[2][64 * 64];  // [d][pos-chunk ^ (d&7)]
  __shared__ __align__(16) u16 Pl[4][16 * 64];   // per-wave P, XOR swizzled
  const int tid = threadIdx.x;
  const int lane = tid & 63;
  const int wave = tid >> 6;
  const int l15 = lane & 15;
  const int g = lane >> 4;
  const int qblk = blockIdx.x;
  const int bh = blockIdx.y;
  const int b = bh >> 4;
  const int h = bh & 15;
  const int qrow = qblk * 64 + wave * 16;

  short8 aq0, aq1;
  {
    const u16* qp = qb + ((size_t)(b * SEQ + qrow + l15)) * E_DIM + h * DH + g * 8;
    aq0 = *(const short8*)(qp);
    aq1 = *(const short8*)(qp + 32);
  }

  f32x4 o[4] = {};
  float lsum[4] = {};

  u16* myPl = Pl[wave];

  const int srow = tid >> 3;  // 0..31
  const int sch = tid & 7;    // 0..7 (16B chunk)
  const int r0 = srow, r1 = 32 + srow;
  const u16* pv0 = vb + ((size_t)(b * SEQ) + r0) * E_DIM + h * DH + ((sch ^ (r0 & 7)) * 8);
  const u16* pv1 = vb + ((size_t)(b * SEQ) + r1) * E_DIM + h * DH + ((sch ^ (r1 & 7)) * 8);
  const u16* pt0 = vtb + ((size_t)bh * DH + r0) * SEQ + ((sch ^ (r0 & 7)) * 8);
  const u16* pt1 = vtb + ((size_t)bh * DH + r1) * SEQ + ((sch ^ (r1 & 7)) * 8);

#define STAGE(buf)                                      \
  {                                                     \
    gl2lds16(pv0, Vs[buf] + tid * 8);                   \
    gl2lds16(pv1, Vs[buf] + 2048 + tid * 8);            \
    gl2lds16(pt0, Vts[buf] + tid * 8);                  \
    gl2lds16(pt1, Vts[buf] + 2048 + tid * 8);           \
    pv0 += 64 * E_DIM; pv1 += 64 * E_DIM;               \
    pt0 += 64; pt1 += 64;                               \
  }

  STAGE(0)
  int cur = 0;

  for (int kc = 0; kc < SEQ; kc += 64) {
    asm volatile("s_barrier" ::: "memory");  // A: readers of buf[nxt] done
    if (kc + 64 < SEQ) {
      STAGE(cur ^ 1)
      asm volatile("s_waitcnt vmcnt(4)" ::: "memory");
    } else {
      asm volatile("s_waitcnt vmcnt(0)" ::: "memory");
    }
    asm volatile("s_barrier" ::: "memory");  // B: everyone's buf[cur] loaded

    const u16* VsC = Vs[cur];
    const u16* VtsC = Vts[cur];

    // S-tile: 16 q x 64 keys
    f32x4 s[4];
#pragma unroll
    for (int nt = 0; nt < 4; nt++) {
      const int key = nt * 16 + l15;
      const u16* vr = VsC + key * 64;
      short8 b0 = *(const short8*)(vr + ((g ^ (key & 7)) * 8));
      short8 b1 = *(const short8*)(vr + (((4 + g) ^ (key & 7)) * 8));
      f32x4 z = {};
      z = __builtin_amdgcn_mfma_f32_16x16x32_bf16(aq0, b0, z, 0, 0, 0);
      z = __builtin_amdgcn_mfma_f32_16x16x32_bf16(aq1, b1, z, 0, 0, 0);
      s[nt] = z;
    }

    // p = exp2(s) (log2e folded into Q); pack 4 truncated-bf16 -> one b64
    // store per row. sigma: key nt*16+l15 -> pos l15*4+nt; phys chunk =
    // (l15>>1) ^ (row&7).
#pragma unroll
    for (int r = 0; r < 4; r++) {
      const int row = g * 4 + r;
      union { float f; unsigned u; } p0, p1, p2, p3;
      p0.f = __builtin_amdgcn_exp2f(s[0][r]);
      p1.f = __builtin_amdgcn_exp2f(s[1][r]);
      p2.f = __builtin_amdgcn_exp2f(s[2][r]);
      p3.f = __builtin_amdgcn_exp2f(s[3][r]);
      union { unsigned u; float f; } t0, t1, t2, t3;
      t0.u = p0.u & 0xffff0000u;
      t1.u = p1.u & 0xffff0000u;
      t2.u = p2.u & 0xffff0000u;
      t3.u = p3.u & 0xffff0000u;
      lsum[r] += (t0.f + t1.f) + (t2.f + t3.f);
      uint2 pk;
      pk.x = __builtin_amdgcn_perm(p1.u, p0.u, 0x07060302u);
      pk.y = __builtin_amdgcn_perm(p3.u, p2.u, 0x07060302u);
      *(uint2*)(myPl + row * 64 + (((l15 >> 1) ^ (row & 7)) << 3) + ((l15 & 1) << 2)) = pk;
    }

    // PV: 2 k-steps of 32 positions
#pragma unroll
    for (int ks = 0; ks < 2; ks++) {
      const int rp = l15;
      short8 ap = *(const short8*)(myPl + rp * 64 + (((ks * 4 + g) ^ (rp & 7)) << 3));
#pragma unroll
      for (int dt = 0; dt < 4; dt++) {
        const int d = dt * 16 + l15;
        short8 bv = *(const short8*)(VtsC + d * 64 + (((ks * 4 + g) ^ (d & 7)) * 8));
        o[dt] = __builtin_amdgcn_mfma_f32_16x16x32_bf16(ap, bv, o[dt], 0, 0, 0);
      }
    }
    cur ^= 1;
  }
#undef STAGE

#pragma unroll
  for (int r = 0; r < 4; r++) {
    float l = lsum[r];
    l += __shfl_xor(l, 1);
    l += __shfl_xor(l, 2);
    l += __shfl_xor(l, 4);
    l += __shfl_xor(l, 8);
    const float inv = 1.0f / l;
    size_t base = ((size_t)(b * SEQ + qrow + g * 4 + r)) * E_DIM + h * DH;
#pragma unroll
    for (int dt = 0; dt < 4; dt++)
      ctxb[base + dt * 16 + l15] = f2b(o[dt][r] * inv);
  }
}

// ---------------------------------------------------------------------------
// out = LayerNorm(X + Y0 + Y1); Y0/Y1 = split-K partials. In-place safe when
// out32 aliases an input (each thread reads its own row elements first).
// ---------------------------------------------------------------------------
__global__ __launch_bounds__(256)
void add_ln3(const float* __restrict__ X, const float* __restrict__ Y0,
             const float* __restrict__ Y1,
             const float* __restrict__ gam, const float* __restrict__ bet,
             float* __restrict__ out32, u16* __restrict__ out16) {
  const int row = blockIdx.x;
  const int tid = threadIdx.x;
  const size_t base = (size_t)row * E_DIM;
  float v[4];
  float s = 0.f, sq = 0.f;
#pragma unroll
  for (int i = 0; i < 4; i++) {
    const int c = tid + i * 256;
    float x = X[base + c] + Y0[base + c] + Y1[base + c];
    v[i] = x; s += x; sq += x * x;
  }
#pragma unroll
  for (int off = 32; off; off >>= 1) {
    s += __shfl_xor(s, off);
    sq += __shfl_xor(sq, off);
  }
  __shared__ float sh[8];
  const int wave = tid >> 6, lane = tid & 63;
  if (lane == 0) { sh[wave] = s; sh[4 + wave] = sq; }
  __syncthreads();
  s = sh[0] + sh[1] + sh[2] + sh[3];
  sq = sh[4] + sh[5] + sh[6] + sh[7];
  const float mean = s * (1.f / 1024.f);
  const float var = sq * (1.f / 1024.f) - mean * mean;
  const float rstd = rsqrtf(var + 1e-5f);
#pragma unroll
  for (int i = 0; i < 4; i++) {
    const int c = tid + i * 256;
    float y = (v[i] - mean) * rstd * gam[c] + bet[c];
    out32[base + c] = y;
    if (out16) out16[base + c] = f2b(y);
  }
}

// ---------------------------------------------------------------------------
extern "C" void kernel_launch(void* const* d_in, const int* in_sizes, int n_in,
                              void* d_out, int out_size, void* d_ws, size_t ws_size,
                              hipStream_t stream) {
  const float* x   = (const float*)d_in[0];
  const float* Wq  = (const float*)d_in[1];
  const float* bq  = (const float*)d_in[2];
  // d_in[3]=Wk, d_in[4]=bk -- dead code in the reference (scores use Q@V^T)
  const float* Wv  = (const float*)d_in[5];
  const float* bv  = (const float*)d_in[6];
  const float* Wo  = (const float*)d_in[7];
  const float* bo  = (const float*)d_in[8];
  const float* g1  = (const float*)d_in[9];
  const float* b1  = (const float*)d_in[10];
  const float* W1  = (const float*)d_in[11];
  const float* bf1 = (const float*)d_in[12];
  const float* W2  = (const float*)d_in[13];
  const float* bf2 = (const float*)d_in[14];
  const float* g2  = (const float*)d_in[15];
  const float* b2  = (const float*)d_in[16];

  char* w = (char*)d_ws;
  const size_t MB = 1024ull * 1024ull;
  u16*   xb   = (u16*)(w + 0);          //  8MB
  u16*   h1   = (u16*)(w + 8 * MB);     // 32MB
  u16*   qb   = (u16*)(w + 8 * MB);     //  8MB
  u16*   vb   = (u16*)(w + 16 * MB);    //  8MB
  u16*   vtb  = (u16*)(w + 24 * MB);    //  8MB
  u16*   ctxb = (u16*)(w + 32 * MB);    //  8MB
  float* att0 = (float*)(w + 40 * MB);  // 32MB (both Wo partials, contiguous)
  float* ff0  = (float*)(w + 40 * MB);  // 32MB (both FF2 partials, contiguous)
  float* pa   = (float*)(w + 72 * MB);  // 16MB
  u16*   pab  = (u16*)(w + 88 * MB);    //  8MB
  u16*   WqT  = (u16*)(w + 96 * MB);    //  2MB (WqT|WvT contiguous)
  u16*   WvT  = (u16*)(w + 98 * MB);    //  2MB
  u16*   WoT  = (u16*)(w + 100 * MB);   //  2MB
  u16*   W1T  = (u16*)(w + 102 * MB);   //  8MB
  u16*   W2T  = (u16*)(w + 110 * MB);   //  8MB -> 118MB total

  transpose_w<<<dim3(32, 32), 256, 0, stream>>>(Wq, WqT, 1024, 1024);
  transpose_w<<<dim3(32, 32), 256, 0, stream>>>(Wv, WvT, 1024, 1024);
  transpose_w<<<dim3(32, 32), 256, 0, stream>>>(Wo, WoT, 1024, 1024);
  transpose_w<<<dim3(32, 128), 256, 0, stream>>>(W1, W1T, 1024, 4096);
  transpose_w<<<dim3(128, 32), 256, 0, stream>>>(W2, W2T, 4096, 1024);
  f32_to_bf16<<<TOKENS * E_DIM / 4 / 256, 256, 0, stream>>>(x, xb);

  gemm_qv64<<<dim3(32, 32), 256, 0, stream>>>(xb, WqT, bq, bv, qb, vb, 1024);
  transpose_v<<<dim3(32, 32), 256, 0, stream>>>(vb, vtb);
  attn_kernel<<<dim3(32, 32), 256, 0, stream>>>(qb, vb, vtb, ctxb);
  gemm_wide_sk<<<dim3(256), 512, 0, stream>>>(ctxb, WoT, bo, att0, 1024, 1024);
  add_ln3<<<TOKENS, 256, 0, stream>>>(x, att0, att0 + (size_t)TOKENS * 1024, g1, b1, pa, pab);
  gemm256<1, 1><<<dim3(256), 512, 0, stream>>>(pab, W1T, bf1, h1, 4096, 1024);
  gemm_wide_sk<<<dim3(256), 512, 0, stream>>>(h1, W2T, bf2, ff0, 1024, 4096);
  add_ln3<<<TOKENS, 256, 0, stream>>>(pa, ff0, ff0 + (size_t)TOKENS * 1024, g2, b2, (float*)d_out, (u16*)nullptr);
}

// Round 4
// 368.482 us; speedup vs baseline: 1.0584x; 1.0584x over previous
//
#include <hip/hip_runtime.h>
#include <stdint.h>

typedef unsigned short u16;
typedef __attribute__((ext_vector_type(8))) short short8;
typedef __attribute__((ext_vector_type(4))) float f32x4;
typedef __attribute__((ext_vector_type(4))) unsigned short u16x4;

#define TOKENS 4096
#define E_DIM 1024
#define F_DIM 4096
#define SEQ 2048
#define NH 16
#define DH 64

__device__ __forceinline__ u16 f2b(float f) {
  union { float f; unsigned u; } v; v.f = f;
  unsigned r = v.u + 0x7fffu + ((v.u >> 16) & 1u);
  return (u16)(r >> 16);
}

__device__ __forceinline__ void gl2lds16(const u16* g, u16* l) {
  __builtin_amdgcn_global_load_lds(
      (const __attribute__((address_space(1))) unsigned int*)(size_t)(g),
      (__attribute__((address_space(3))) unsigned int*)(unsigned int)(size_t)(l),
      16, 0, 0);
}

// ---------------------------------------------------------------------------
// GEMM LDS chunk swizzle (round-4): physical 16B-chunk p of row r holds
// global chunk c = p ^ s(r), s(r) = (r>>1)&3.
//  - staging: lane l (quad-contiguous: row l>>2, phys chunk l&3) loads global
//    chunk (l&3)^s(row) -> the quad still covers one 64B line (coalescing
//    kept; round-3's frag-order map scattered 16 lanes over 16 rows and
//    cost ~4x L2 requests on staging).
//  - frag read: lane(row=l&15, chunk g=l>>4) reads offset r*64B+((g^s(r))*16B;
//    8-lane service group start banks {0,16,4,20,8,24,12,28} -> conflict-free
//    (old row-major read was 4-way per group: the 4.19M SQ_LDS_BANK_CONFLICT).
// ---------------------------------------------------------------------------

// ---------------------------------------------------------------------------
__global__ __launch_bounds__(256)
void transpose_w(const float* __restrict__ W, u16* __restrict__ Wt, int K, int N) {
  __shared__ float tile[32][33];
  const int kb = blockIdx.x * 32, nb = blockIdx.y * 32;
  const int tx = threadIdx.x & 31, ty = threadIdx.x >> 5;  // 32 x 8
#pragma unroll
  for (int i = 0; i < 32; i += 8)
    tile[ty + i][tx] = W[(size_t)(kb + ty + i) * N + nb + tx];
  __syncthreads();
#pragma unroll
  for (int i = 0; i < 32; i += 8)
    Wt[(size_t)(nb + ty + i) * K + kb + tx] = f2b(tile[tx][ty + i]);
}

// ---------------------------------------------------------------------------
__global__ __launch_bounds__(256)
void f32_to_bf16(const float* __restrict__ in, u16* __restrict__ out) {
  const int i = blockIdx.x * 256 + threadIdx.x;
  f32x4 f = ((const f32x4*)in)[i];
  u16x4 u;
#pragma unroll
  for (int j = 0; j < 4; j++) u[j] = f2b(f[j]);
  ((u16x4*)out)[i] = u;
}

// ---------------------------------------------------------------------------
// v (token-major bf16) -> vt [B][H][DH][SEQ], key dimension sigma-permuted
// within each 64-key window: position p holds key (p&3)*16 + (p>>2).
// ---------------------------------------------------------------------------
__global__ __launch_bounds__(256)
void transpose_v(const u16* __restrict__ vsrc, u16* __restrict__ vt) {
  __shared__ u16 tile[64][66];
  const int kb = blockIdx.x * 64;
  const int bh = blockIdx.y;
  const int b = bh >> 4, h = bh & 15;
  {
    const int d = threadIdx.x & 63, r = threadIdx.x >> 6;  // 64 x 4
#pragma unroll
    for (int i = 0; i < 64; i += 4)
      tile[r + i][d] = vsrc[(size_t)(b * SEQ + kb + r + i) * E_DIM + h * DH + d];
  }
  __syncthreads();
  {
    const int pos = threadIdx.x & 63;
    const int srck = (pos & 3) * 16 + (pos >> 2);  // sigma^{-1}(pos)
#pragma unroll
    for (int j = 0; j < 64; j += 4) {
      const int d = (threadIdx.x >> 6) + j;
      vt[(size_t)(bh * DH + d) * SEQ + kb + pos] = tile[srck][d];
    }
  }
}

// ---------------------------------------------------------------------------
// gemm256: 256x256 tile, BK=32, phased schedule with counted vmcnt.
// Round-4: quad-contiguous staging + chunk-XOR swizzle (see top comment).
// ---------------------------------------------------------------------------
template <int RELU, int OUTBF>
__global__ __launch_bounds__(512)
void gemm256(const u16* __restrict__ A, const u16* __restrict__ Bt,
             const float* __restrict__ bias, void* __restrict__ Cout,
             int N, int K) {
  __shared__ __align__(16) u16 lds[3][2][8192];  // [buf][A/B][16 subtiles x 512]
  const int tid = threadIdx.x;
  const int lane = tid & 63, wave = tid >> 6;
  const int wm = wave >> 2, wn = wave & 3;  // 2 x 4 wave grid
  const int l15 = lane & 15, g = lane >> 4;

  const int bid = blockIdx.x;
  const int xcd = bid & 7, idx = bid >> 3;          // idx in 0..31
  const int mT = (xcd >> 2) * 8 + (idx >> 2);       // 0..15
  const int nT = (xcd & 3) * 4 + (idx & 3);         // 0..15
  const int mBlk = mT * 256, nBlk = nT * 256;

  const u16* Ab = A + (size_t)mBlk * K;
  const u16* Bb = Bt + (size_t)nBlk * K;

  // quad-contiguous staging with chunk-XOR source permutation
  const int srow = lane >> 2;
  const int scolx = ((lane & 3) ^ ((lane >> 3) & 3)) * 8;  // (l&3)^s(l>>2)
  const u16* sa0 = Ab + (size_t)(wave * 16 + srow) * K + scolx;
  const u16* sa1 = Ab + (size_t)((8 + wave) * 16 + srow) * K + scolx;
  const u16* sb0 = Bb + (size_t)(wave * 16 + srow) * K + scolx;
  const u16* sb1 = Bb + (size_t)((8 + wave) * 16 + srow) * K + scolx;

  // frag read offset: r*32 u16 + ((g ^ s(r))*8 u16, s(r)=(r>>1)&3
  const int fo = l15 * 32 + ((g ^ ((l15 >> 1) & 3)) << 3);

  f32x4 acc[8][4] = {};

  const int NT = K >> 5;  // K-tiles of 32

#define STAGE_A(buf, t)                                             \
  {                                                                 \
    gl2lds16(sa0 + (size_t)(t) * 32, &lds[buf][0][wave * 512 + lane * 8]);       \
    gl2lds16(sa1 + (size_t)(t) * 32, &lds[buf][0][(8 + wave) * 512 + lane * 8]); \
  }
#define STAGE_B(buf, t)                                             \
  {                                                                 \
    gl2lds16(sb0 + (size_t)(t) * 32, &lds[buf][1][wave * 512 + lane * 8]);       \
    gl2lds16(sb1 + (size_t)(t) * 32, &lds[buf][1][(8 + wave) * 512 + lane * 8]); \
  }

  STAGE_A(0, 0) STAGE_B(0, 0)
  STAGE_A(1, 1) STAGE_B(1, 1)
  asm volatile("s_waitcnt vmcnt(4)" ::: "memory");
  asm volatile("s_barrier" ::: "memory");

  int buf = 0, sbuf = 2;
  for (int t = 0; t < NT; ++t) {
    const u16* As_ = &lds[buf][0][wm * (8 * 512)];
    const u16* Bs_ = &lds[buf][1][wn * (4 * 512)];

    short8 af[4], bfr[4];
    // ---- phase 1 ----
#pragma unroll
    for (int i = 0; i < 4; i++)
      af[i] = *(const short8*)(As_ + i * 512 + fo);
#pragma unroll
    for (int i = 0; i < 4; i++)
      bfr[i] = *(const short8*)(Bs_ + i * 512 + fo);
    if (t + 2 < NT) STAGE_A(sbuf, t + 2)
    asm volatile("s_barrier" ::: "memory");
    asm volatile("s_waitcnt lgkmcnt(0)" ::: "memory");
    __builtin_amdgcn_sched_barrier(0);
    __builtin_amdgcn_s_setprio(1);
#pragma unroll
    for (int mg = 0; mg < 4; mg++)
#pragma unroll
      for (int ng = 0; ng < 4; ng++)
        acc[mg][ng] = __builtin_amdgcn_mfma_f32_16x16x32_bf16(af[mg], bfr[ng],
                                                              acc[mg][ng], 0, 0, 0);
    __builtin_amdgcn_s_setprio(0);
    asm volatile("s_barrier" ::: "memory");

    // ---- phase 2 ----
#pragma unroll
    for (int i = 0; i < 4; i++)
      af[i] = *(const short8*)(As_ + (4 + i) * 512 + fo);
    if (t + 2 < NT) STAGE_B(sbuf, t + 2)
    asm volatile("s_barrier" ::: "memory");
    asm volatile("s_waitcnt lgkmcnt(0)" ::: "memory");
    __builtin_amdgcn_sched_barrier(0);
    __builtin_amdgcn_s_setprio(1);
#pragma unroll
    for (int mg = 0; mg < 4; mg++)
#pragma unroll
      for (int ng = 0; ng < 4; ng++)
        acc[4 + mg][ng] = __builtin_amdgcn_mfma_f32_16x16x32_bf16(af[mg], bfr[ng],
                                                                  acc[4 + mg][ng], 0, 0, 0);
    __builtin_amdgcn_s_setprio(0);
    if (t + 2 < NT) asm volatile("s_waitcnt vmcnt(4)" ::: "memory");
    else            asm volatile("s_waitcnt vmcnt(0)" ::: "memory");
    asm volatile("s_barrier" ::: "memory");

    buf = (buf == 2) ? 0 : buf + 1;
    sbuf = (sbuf == 2) ? 0 : sbuf + 1;
  }
#undef STAGE_A
#undef STAGE_B

  const int row0 = mBlk + wm * 128 + g * 4;
  const int col0 = nBlk + wn * 64 + l15;
#pragma unroll
  for (int ng = 0; ng < 4; ng++) {
    const int c = col0 + ng * 16;
    const float bv = bias[c];
#pragma unroll
    for (int mg = 0; mg < 8; mg++) {
#pragma unroll
      for (int r = 0; r < 4; r++) {
        float v = acc[mg][ng][r] + bv;
        if (RELU) v = fmaxf(v, 0.f);
        const size_t o = (size_t)(row0 + mg * 16 + r) * N + c;
        if (OUTBF) ((u16*)Cout)[o] = f2b(v);
        else       ((float*)Cout)[o] = v;
      }
    }
  }
}

// ---------------------------------------------------------------------------
// gemm_wide_sk: 256M x 128N tile, split-K 2, fp32 partials to
// Cout + kz*TOKENS*N (bias on kz==0). Grid = 256 blocks (16 mT x 8 nT x 2 kz),
// 512 threads = 8 waves (4M x 2N), per-wave 64x64 acc[4][4].
// 3-deep LDS ring, ONE barrier per K-step, steady-state vmcnt(3).
// Round-4: quad-contiguous staging + chunk-XOR swizzle (see top comment).
// ---------------------------------------------------------------------------
__global__ __launch_bounds__(512)
void gemm_wide_sk(const u16* __restrict__ A, const u16* __restrict__ Bt,
                  const float* __restrict__ bias, float* __restrict__ Cout,
                  int N, int K) {
  __shared__ __align__(16) u16 lds[3][12288];  // [buf][ A 16x512 | B 8x512 ]
  const int tid = threadIdx.x;
  const int lane = tid & 63, wave = tid >> 6;
  const int wm = wave >> 1, wn = wave & 1;  // 4M x 2N wave grid
  const int l15 = lane & 15, g = lane >> 4;

  const int bid = blockIdx.x;
  const int xcd = bid & 7, idx = bid >> 3;            // idx 0..31
  const int kz = xcd & 1;
  const int nT = ((xcd >> 1) & 1) * 4 + (idx & 3);    // 0..7
  const int mT = (xcd >> 2) * 8 + (idx >> 2);         // 0..15
  const int mBlk = mT * 256, nBlk = nT * 128;
  const int Kh = K >> 1;

  const u16* Ab = A + (size_t)mBlk * K + (size_t)kz * Kh;
  const u16* Bb = Bt + (size_t)nBlk * K + (size_t)kz * Kh;

  const int srow = lane >> 2;
  const int scolx = ((lane & 3) ^ ((lane >> 3) & 3)) * 8;
  const u16* sa0 = Ab + (size_t)(wave * 16 + srow) * K + scolx;
  const u16* sa1 = Ab + (size_t)((8 + wave) * 16 + srow) * K + scolx;
  const u16* sb0 = Bb + (size_t)(wave * 16 + srow) * K + scolx;

  const int fo = l15 * 32 + ((g ^ ((l15 >> 1) & 3)) << 3);

  f32x4 acc[4][4] = {};
  const int NT = Kh >> 5;

#define WSTAGE(buf, t)                                                         \
  {                                                                            \
    gl2lds16(sa0 + (size_t)(t) * 32, &lds[buf][wave * 512 + lane * 8]);        \
    gl2lds16(sa1 + (size_t)(t) * 32, &lds[buf][(8 + wave) * 512 + lane * 8]);  \
    gl2lds16(sb0 + (size_t)(t) * 32, &lds[buf][8192 + wave * 512 + lane * 8]); \
  }

  WSTAGE(0, 0)
  WSTAGE(1, 1)
  asm volatile("s_waitcnt vmcnt(3)" ::: "memory");
  asm volatile("s_barrier" ::: "memory");

  int buf = 0, sbuf = 2;
  for (int t = 0; t < NT; ++t) {
    const u16* As_ = &lds[buf][wm * (4 * 512)];
    const u16* Bs_ = &lds[buf][8192 + wn * (4 * 512)];
    short8 af[4], bfr[4];
#pragma unroll
    for (int i = 0; i < 4; i++)
      af[i] = *(const short8*)(As_ + i * 512 + fo);
#pragma unroll
    for (int i = 0; i < 4; i++)
      bfr[i] = *(const short8*)(Bs_ + i * 512 + fo);
    if (t + 2 < NT) WSTAGE(sbuf, t + 2)
    asm volatile("s_waitcnt lgkmcnt(0)" ::: "memory");
    __builtin_amdgcn_sched_barrier(0);
    __builtin_amdgcn_s_setprio(1);
#pragma unroll
    for (int mi = 0; mi < 4; mi++)
#pragma unroll
      for (int ni = 0; ni < 4; ni++)
        acc[mi][ni] = __builtin_amdgcn_mfma_f32_16x16x32_bf16(af[mi], bfr[ni],
                                                              acc[mi][ni], 0, 0, 0);
    __builtin_amdgcn_s_setprio(0);
    if (t + 2 < NT) asm volatile("s_waitcnt vmcnt(3)" ::: "memory");
    else            asm volatile("s_waitcnt vmcnt(0)" ::: "memory");
    asm volatile("s_barrier" ::: "memory");
    buf = (buf == 2) ? 0 : buf + 1;
    sbuf = (sbuf == 2) ? 0 : sbuf + 1;
  }
#undef WSTAGE

  float* out = Cout + (size_t)kz * TOKENS * N;
  const int row0 = mBlk + wm * 64 + g * 4;
  const int col0 = nBlk + wn * 64 + l15;
#pragma unroll
  for (int ni = 0; ni < 4; ni++) {
    const int c = col0 + ni * 16;
    const float bv = (kz == 0) ? bias[c] : 0.f;
#pragma unroll
    for (int mi = 0; mi < 4; mi++) {
#pragma unroll
      for (int r = 0; r < 4; r++)
        out[(size_t)(row0 + mi * 16 + r) * N + c] = acc[mi][ni][r] + bv;
    }
  }
}

// ---------------------------------------------------------------------------
// Fused Q+V GEMM: Bqv = [WqT | WvT] contiguous (2048 x K). Q half scaled by
// (1/sqrt(Dh)) * log2(e) -- attention uses exp2 directly.
// Round-4: quad-contiguous staging + chunk-XOR swizzle.
// ---------------------------------------------------------------------------
__global__ __launch_bounds__(256)
void gemm_qv64(const u16* __restrict__ A, const u16* __restrict__ Bqv,
               const float* __restrict__ bq, const float* __restrict__ bv,
               u16* __restrict__ qout, u16* __restrict__ vout, int K) {
  __shared__ __align__(16) u16 As[128 * 32];
  __shared__ __align__(16) u16 Bs[64 * 32];
  const int tid = threadIdx.x;
  const int lane = tid & 63, wave = tid >> 6;
  const int mBlk = blockIdx.y * 128, nBlk = blockIdx.x * 64;
  const int isQ = nBlk < 1024;
  const int ncol = isQ ? nBlk : nBlk - 1024;
  const float* bias = isQ ? bq : bv;
  u16* out = isQ ? qout : vout;
  const float oscale = isQ ? 0.125f * 1.44269504088896f : 1.0f;
  const int wm = (wave >> 1) * 64, wn = (wave & 1) * 32;
  const int l15 = lane & 15, g = lane >> 4;

  f32x4 acc[4][2] = {};
  const int srow = lane >> 2;
  const int scolx = ((lane & 3) ^ ((lane >> 3) & 3)) * 8;
  const int fo = l15 * 32 + ((g ^ ((l15 >> 1) & 3)) << 3);

  const u16* Ab = A + (size_t)mBlk * K;
  const u16* Bb = Bqv + (size_t)nBlk * K;

  for (int k0 = 0; k0 < K; k0 += 32) {
    __syncthreads();
    for (int c = wave; c < 8; c += 4)
      gl2lds16(Ab + (size_t)(c * 16 + srow) * K + k0 + scolx, As + c * 512 + lane * 8);
    gl2lds16(Bb + (size_t)(wave * 16 + srow) * K + k0 + scolx, Bs + wave * 512 + lane * 8);
    __syncthreads();

    short8 af[4], bf[2];
#pragma unroll
    for (int i = 0; i < 4; i++)
      af[i] = *(const short8*)(As + ((wm >> 4) + i) * 512 + fo);
#pragma unroll
    for (int i = 0; i < 2; i++)
      bf[i] = *(const short8*)(Bs + ((wn >> 4) + i) * 512 + fo);
#pragma unroll
    for (int mi = 0; mi < 4; mi++)
#pragma unroll
      for (int ni = 0; ni < 2; ni++)
        acc[mi][ni] = __builtin_amdgcn_mfma_f32_16x16x32_bf16(af[mi], bf[ni],
                                                              acc[mi][ni], 0, 0, 0);
  }

  const int row0 = mBlk + wm + g * 4;
  const int col0 = ncol + wn + l15;
#pragma unroll
  for (int ni = 0; ni < 2; ni++) {
    const int c = col0 + ni * 16;
    const float bv_ = bias[c];
#pragma unroll
    for (int mi = 0; mi < 4; mi++) {
#pragma unroll
      for (int r = 0; r < 4; r++) {
        float v = (acc[mi][ni][r] + bv_) * oscale;
        out[(size_t)(row0 + mi * 16 + r) * E_DIM + c] = f2b(v);
      }
    }
  }
}

// ---------------------------------------------------------------------------
// Flash attention v5 (round-1): 4 waves x 16 q-rows, double-buffered staging,
// raw s_barrier + counted vmcnt, exp2 direct. Unchanged this round.
// ---------------------------------------------------------------------------
__global__ __launch_bounds__(256)
void attn_kernel(const u16* __restrict__ qb, const u16* __restrict__ vb,
                 const u16* __restrict__ vtb, u16* __restrict__ ctxb) {
  __shared__ __align__(16) u16 Vs[2][64 * 64];   // [key][d-chunk ^ (key&7)]
  __shared__ __align__(16) u16 Vts[2][64 * 64];  // [d][pos-chunk ^ (d&7)]
  __shared__ __align__(16) u16 Pl[4][16 * 64];   // per-wave P, XOR swizzled
  const int tid = threadIdx.x;
  const int lane = tid & 63;
  const int wave = tid >> 6;
  const int l15 = lane & 15;
  const int g = lane >> 4;
  const int qblk = blockIdx.x;
  const int bh = blockIdx.y;
  const int b = bh >> 4;
  const int h = bh & 15;
  const int qrow = qblk * 64 + wave * 16;

  short8 aq0, aq1;
  {
    const u16* qp = qb + ((size_t)(b * SEQ + qrow + l15)) * E_DIM + h * DH + g * 8;
    aq0 = *(const short8*)(qp);
    aq1 = *(const short8*)(qp + 32);
  }

  f32x4 o[4] = {};
  float lsum[4] = {};

  u16* myPl = Pl[wave];

  const int srow = tid >> 3;  // 0..31
  const int sch = tid & 7;    // 0..7 (16B chunk)
  const int r0 = srow, r1 = 32 + srow;
  const u16* pv0 = vb + ((size_t)(b * SEQ) + r0) * E_DIM + h * DH + ((sch ^ (r0 & 7)) * 8);
  const u16* pv1 = vb + ((size_t)(b * SEQ) + r1) * E_DIM + h * DH + ((sch ^ (r1 & 7)) * 8);
  const u16* pt0 = vtb + ((size_t)bh * DH + r0) * SEQ + ((sch ^ (r0 & 7)) * 8);
  const u16* pt1 = vtb + ((size_t)bh * DH + r1) * SEQ + ((sch ^ (r1 & 7)) * 8);

#define STAGE(buf)                                      \
  {                                                     \
    gl2lds16(pv0, Vs[buf] + tid * 8);                   \
    gl2lds16(pv1, Vs[buf] + 2048 + tid * 8);            \
    gl2lds16(pt0, Vts[buf] + tid * 8);                  \
    gl2lds16(pt1, Vts[buf] + 2048 + tid * 8);           \
    pv0 += 64 * E_DIM; pv1 += 64 * E_DIM;               \
    pt0 += 64; pt1 += 64;                               \
  }

  STAGE(0)
  int cur = 0;

  for (int kc = 0; kc < SEQ; kc += 64) {
    asm volatile("s_barrier" ::: "memory");  // A: readers of buf[nxt] done
    if (kc + 64 < SEQ) {
      STAGE(cur ^ 1)
      asm volatile("s_waitcnt vmcnt(4)" ::: "memory");
    } else {
      asm volatile("s_waitcnt vmcnt(0)" ::: "memory");
    }
    asm volatile("s_barrier" ::: "memory");  // B: everyone's buf[cur] loaded

    const u16* VsC = Vs[cur];
    const u16* VtsC = Vts[cur];

    // S-tile: 16 q x 64 keys
    f32x4 s[4];
#pragma unroll
    for (int nt = 0; nt < 4; nt++) {
      const int key = nt * 16 + l15;
      const u16* vr = VsC + key * 64;
      short8 b0 = *(const short8*)(vr + ((g ^ (key & 7)) * 8));
      short8 b1 = *(const short8*)(vr + (((4 + g) ^ (key & 7)) * 8));
      f32x4 z = {};
      z = __builtin_amdgcn_mfma_f32_16x16x32_bf16(aq0, b0, z, 0, 0, 0);
      z = __builtin_amdgcn_mfma_f32_16x16x32_bf16(aq1, b1, z, 0, 0, 0);
      s[nt] = z;
    }

    // p = exp2(s) (log2e folded into Q); pack 4 truncated-bf16 -> one b64
    // store per row. sigma: key nt*16+l15 -> pos l15*4+nt; phys chunk =
    // (l15>>1) ^ (row&7).
#pragma unroll
    for (int r = 0; r < 4; r++) {
      const int row = g * 4 + r;
      union { float f; unsigned u; } p0, p1, p2, p3;
      p0.f = __builtin_amdgcn_exp2f(s[0][r]);
      p1.f = __builtin_amdgcn_exp2f(s[1][r]);
      p2.f = __builtin_amdgcn_exp2f(s[2][r]);
      p3.f = __builtin_amdgcn_exp2f(s[3][r]);
      union { unsigned u; float f; } t0, t1, t2, t3;
      t0.u = p0.u & 0xffff0000u;
      t1.u = p1.u & 0xffff0000u;
      t2.u = p2.u & 0xffff0000u;
      t3.u = p3.u & 0xffff0000u;
      lsum[r] += (t0.f + t1.f) + (t2.f + t3.f);
      uint2 pk;
      pk.x = __builtin_amdgcn_perm(p1.u, p0.u, 0x07060302u);
      pk.y = __builtin_amdgcn_perm(p3.u, p2.u, 0x07060302u);
      *(uint2*)(myPl + row * 64 + (((l15 >> 1) ^ (row & 7)) << 3) + ((l15 & 1) << 2)) = pk;
    }

    // PV: 2 k-steps of 32 positions
#pragma unroll
    for (int ks = 0; ks < 2; ks++) {
      const int rp = l15;
      short8 ap = *(const short8*)(myPl + rp * 64 + (((ks * 4 + g) ^ (rp & 7)) << 3));
#pragma unroll
      for (int dt = 0; dt < 4; dt++) {
        const int d = dt * 16 + l15;
        short8 bv = *(const short8*)(VtsC + d * 64 + (((ks * 4 + g) ^ (d & 7)) * 8));
        o[dt] = __builtin_amdgcn_mfma_f32_16x16x32_bf16(ap, bv, o[dt], 0, 0, 0);
      }
    }
    cur ^= 1;
  }
#undef STAGE

#pragma unroll
  for (int r = 0; r < 4; r++) {
    float l = lsum[r];
    l += __shfl_xor(l, 1);
    l += __shfl_xor(l, 2);
    l += __shfl_xor(l, 4);
    l += __shfl_xor(l, 8);
    const float inv = 1.0f / l;
    size_t base = ((size_t)(b * SEQ + qrow + g * 4 + r)) * E_DIM + h * DH;
#pragma unroll
    for (int dt = 0; dt < 4; dt++)
      ctxb[base + dt * 16 + l15] = f2b(o[dt][r] * inv);
  }
}

// ---------------------------------------------------------------------------
// out = LayerNorm(X + Y0 + Y1); Y0/Y1 = split-K partials. In-place safe when
// out32 aliases an input (each thread reads its own row elements first).
// ---------------------------------------------------------------------------
__global__ __launch_bounds__(256)
void add_ln3(const float* __restrict__ X, const float* __restrict__ Y0,
             const float* __restrict__ Y1,
             const float* __restrict__ gam, const float* __restrict__ bet,
             float* __restrict__ out32, u16* __restrict__ out16) {
  const int row = blockIdx.x;
  const int tid = threadIdx.x;
  const size_t base = (size_t)row * E_DIM;
  float v[4];
  float s = 0.f, sq = 0.f;
#pragma unroll
  for (int i = 0; i < 4; i++) {
    const int c = tid + i * 256;
    float x = X[base + c] + Y0[base + c] + Y1[base + c];
    v[i] = x; s += x; sq += x * x;
  }
#pragma unroll
  for (int off = 32; off; off >>= 1) {
    s += __shfl_xor(s, off);
    sq += __shfl_xor(sq, off);
  }
  __shared__ float sh[8];
  const int wave = tid >> 6, lane = tid & 63;
  if (lane == 0) { sh[wave] = s; sh[4 + wave] = sq; }
  __syncthreads();
  s = sh[0] + sh[1] + sh[2] + sh[3];
  sq = sh[4] + sh[5] + sh[6] + sh[7];
  const float mean = s * (1.f / 1024.f);
  const float var = sq * (1.f / 1024.f) - mean * mean;
  const float rstd = rsqrtf(var + 1e-5f);
#pragma unroll
  for (int i = 0; i < 4; i++) {
    const int c = tid + i * 256;
    float y = (v[i] - mean) * rstd * gam[c] + bet[c];
    out32[base + c] = y;
    if (out16) out16[base + c] = f2b(y);
  }
}

// ---------------------------------------------------------------------------
extern "C" void kernel_launch(void* const* d_in, const int* in_sizes, int n_in,
                              void* d_out, int out_size, void* d_ws, size_t ws_size,
                              hipStream_t stream) {
  const float* x   = (const float*)d_in[0];
  const float* Wq  = (const float*)d_in[1];
  const float* bq  = (const float*)d_in[2];
  // d_in[3]=Wk, d_in[4]=bk -- dead code in the reference (scores use Q@V^T)
  const float* Wv  = (const float*)d_in[5];
  const float* bv  = (const float*)d_in[6];
  const float* Wo  = (const float*)d_in[7];
  const float* bo  = (const float*)d_in[8];
  const float* g1  = (const float*)d_in[9];
  const float* b1  = (const float*)d_in[10];
  const float* W1  = (const float*)d_in[11];
  const float* bf1 = (const float*)d_in[12];
  const float* W2  = (const float*)d_in[13];
  const float* bf2 = (const float*)d_in[14];
  const float* g2  = (const float*)d_in[15];
  const float* b2  = (const float*)d_in[16];

  char* w = (char*)d_ws;
  const size_t MB = 1024ull * 1024ull;
  u16*   xb   = (u16*)(w + 0);          //  8MB
  u16*   h1   = (u16*)(w + 8 * MB);     // 32MB
  u16*   qb   = (u16*)(w + 8 * MB);     //  8MB
  u16*   vb   = (u16*)(w + 16 * MB);    //  8MB
  u16*   vtb  = (u16*)(w + 24 * MB);    //  8MB
  u16*   ctxb = (u16*)(w + 32 * MB);    //  8MB
  float* att0 = (float*)(w + 40 * MB);  // 32MB (both Wo partials, contiguous)
  float* ff0  = (float*)(w + 40 * MB);  // 32MB (both FF2 partials, contiguous)
  float* pa   = (float*)(w + 72 * MB);  // 16MB
  u16*   pab  = (u16*)(w + 88 * MB);    //  8MB
  u16*   WqT  = (u16*)(w + 96 * MB);    //  2MB (WqT|WvT contiguous)
  u16*   WvT  = (u16*)(w + 98 * MB);    //  2MB
  u16*   WoT  = (u16*)(w + 100 * MB);   //  2MB
  u16*   W1T  = (u16*)(w + 102 * MB);   //  8MB
  u16*   W2T  = (u16*)(w + 110 * MB);   //  8MB -> 118MB total

  transpose_w<<<dim3(32, 32), 256, 0, stream>>>(Wq, WqT, 1024, 1024);
  transpose_w<<<dim3(32, 32), 256, 0, stream>>>(Wv, WvT, 1024, 1024);
  transpose_w<<<dim3(32, 32), 256, 0, stream>>>(Wo, WoT, 1024, 1024);
  transpose_w<<<dim3(32, 128), 256, 0, stream>>>(W1, W1T, 1024, 4096);
  transpose_w<<<dim3(128, 32), 256, 0, stream>>>(W2, W2T, 4096, 1024);
  f32_to_bf16<<<TOKENS * E_DIM / 4 / 256, 256, 0, stream>>>(x, xb);

  gemm_qv64<<<dim3(32, 32), 256, 0, stream>>>(xb, WqT, bq, bv, qb, vb, 1024);
  transpose_v<<<dim3(32, 32), 256, 0, stream>>>(vb, vtb);
  attn_kernel<<<dim3(32, 32), 256, 0, stream>>>(qb, vb, vtb, ctxb);
  gemm_wide_sk<<<dim3(256), 512, 0, stream>>>(ctxb, WoT, bo, att0, 1024, 1024);
  add_ln3<<<TOKENS, 256, 0, stream>>>(x, att0, att0 + (size_t)TOKENS * 1024, g1, b1, pa, pab);
  gemm256<1, 1><<<dim3(256), 512, 0, stream>>>(pab, W1T, bf1, h1, 4096, 1024);
  gemm_wide_sk<<<dim3(256), 512, 0, stream>>>(h1, W2T, bf2, ff0, 1024, 4096);
  add_ln3<<<TOKENS, 256, 0, stream>>>(pa, ff0, ff0 + (size_t)TOKENS * 1024, g2, b2, (float*)d_out, (u16*)nullptr);
}

// Round 5
// 352.072 us; speedup vs baseline: 1.1077x; 1.0466x over previous
//
#include <hip/hip_runtime.h>
#include <stdint.h>

typedef unsigned short u16;
typedef __attribute__((ext_vector_type(8))) short short8;
typedef __attribute__((ext_vector_type(4))) float f32x4;
typedef __attribute__((ext_vector_type(4))) unsigned short u16x4;

#define TOKENS 4096
#define E_DIM 1024
#define F_DIM 4096
#define SEQ 2048
#define NH 16
#define DH 64

__device__ __forceinline__ u16 f2b(float f) {
  union { float f; unsigned u; } v; v.f = f;
  unsigned r = v.u + 0x7fffu + ((v.u >> 16) & 1u);
  return (u16)(r >> 16);
}

__device__ __forceinline__ void gl2lds16(const u16* g, u16* l) {
  __builtin_amdgcn_global_load_lds(
      (const __attribute__((address_space(1))) unsigned int*)(size_t)(g),
      (__attribute__((address_space(3))) unsigned int*)(unsigned int)(size_t)(l),
      16, 0, 0);
}

// ---------------------------------------------------------------------------
// GEMM LDS chunk swizzle (round-4): physical 16B-chunk p of row r holds
// global chunk c = p ^ s(r), s(r) = (r>>1)&3.
//  - staging: lane l (quad-contiguous: row l>>2, phys chunk l&3) loads global
//    chunk (l&3)^s(row) -> the quad still covers one 64B line (coalescing
//    kept); frag read is conflict-free (verified: round-3 390 -> round-4 368).
// ---------------------------------------------------------------------------

// ---------------------------------------------------------------------------
__global__ __launch_bounds__(256)
void transpose_w(const float* __restrict__ W, u16* __restrict__ Wt, int K, int N) {
  __shared__ float tile[32][33];
  const int kb = blockIdx.x * 32, nb = blockIdx.y * 32;
  const int tx = threadIdx.x & 31, ty = threadIdx.x >> 5;  // 32 x 8
#pragma unroll
  for (int i = 0; i < 32; i += 8)
    tile[ty + i][tx] = W[(size_t)(kb + ty + i) * N + nb + tx];
  __syncthreads();
#pragma unroll
  for (int i = 0; i < 32; i += 8)
    Wt[(size_t)(nb + ty + i) * K + kb + tx] = f2b(tile[tx][ty + i]);
}

// ---------------------------------------------------------------------------
__global__ __launch_bounds__(256)
void f32_to_bf16(const float* __restrict__ in, u16* __restrict__ out) {
  const int i = blockIdx.x * 256 + threadIdx.x;
  f32x4 f = ((const f32x4*)in)[i];
  u16x4 u;
#pragma unroll
  for (int j = 0; j < 4; j++) u[j] = f2b(f[j]);
  ((u16x4*)out)[i] = u;
}

// ---------------------------------------------------------------------------
// v (token-major bf16) -> vt [B][H][DH][SEQ], key dimension sigma-permuted
// within each 64-key window: position p holds key (p&3)*16 + (p>>2).
// ---------------------------------------------------------------------------
__global__ __launch_bounds__(256)
void transpose_v(const u16* __restrict__ vsrc, u16* __restrict__ vt) {
  __shared__ u16 tile[64][66];
  const int kb = blockIdx.x * 64;
  const int bh = blockIdx.y;
  const int b = bh >> 4, h = bh & 15;
  {
    const int d = threadIdx.x & 63, r = threadIdx.x >> 6;  // 64 x 4
#pragma unroll
    for (int i = 0; i < 64; i += 4)
      tile[r + i][d] = vsrc[(size_t)(b * SEQ + kb + r + i) * E_DIM + h * DH + d];
  }
  __syncthreads();
  {
    const int pos = threadIdx.x & 63;
    const int srck = (pos & 3) * 16 + (pos >> 2);  // sigma^{-1}(pos)
#pragma unroll
    for (int j = 0; j < 64; j += 4) {
      const int d = (threadIdx.x >> 6) + j;
      vt[(size_t)(bh * DH + d) * SEQ + kb + pos] = tile[srck][d];
    }
  }
}

// ---------------------------------------------------------------------------
// gemm256: 256x256 tile, BK=32, phased schedule with counted vmcnt.
// Quad-contiguous staging + chunk-XOR swizzle (round-4, verified).
// ---------------------------------------------------------------------------
template <int RELU, int OUTBF>
__global__ __launch_bounds__(512)
void gemm256(const u16* __restrict__ A, const u16* __restrict__ Bt,
             const float* __restrict__ bias, void* __restrict__ Cout,
             int N, int K) {
  __shared__ __align__(16) u16 lds[3][2][8192];  // [buf][A/B][16 subtiles x 512]
  const int tid = threadIdx.x;
  const int lane = tid & 63, wave = tid >> 6;
  const int wm = wave >> 2, wn = wave & 3;  // 2 x 4 wave grid
  const int l15 = lane & 15, g = lane >> 4;

  const int bid = blockIdx.x;
  const int xcd = bid & 7, idx = bid >> 3;          // idx in 0..31
  const int mT = (xcd >> 2) * 8 + (idx >> 2);       // 0..15
  const int nT = (xcd & 3) * 4 + (idx & 3);         // 0..15
  const int mBlk = mT * 256, nBlk = nT * 256;

  const u16* Ab = A + (size_t)mBlk * K;
  const u16* Bb = Bt + (size_t)nBlk * K;

  const int srow = lane >> 2;
  const int scolx = ((lane & 3) ^ ((lane >> 3) & 3)) * 8;  // (l&3)^s(l>>2)
  const u16* sa0 = Ab + (size_t)(wave * 16 + srow) * K + scolx;
  const u16* sa1 = Ab + (size_t)((8 + wave) * 16 + srow) * K + scolx;
  const u16* sb0 = Bb + (size_t)(wave * 16 + srow) * K + scolx;
  const u16* sb1 = Bb + (size_t)((8 + wave) * 16 + srow) * K + scolx;

  const int fo = l15 * 32 + ((g ^ ((l15 >> 1) & 3)) << 3);

  f32x4 acc[8][4] = {};

  const int NT = K >> 5;  // K-tiles of 32

#define STAGE_A(buf, t)                                             \
  {                                                                 \
    gl2lds16(sa0 + (size_t)(t) * 32, &lds[buf][0][wave * 512 + lane * 8]);       \
    gl2lds16(sa1 + (size_t)(t) * 32, &lds[buf][0][(8 + wave) * 512 + lane * 8]); \
  }
#define STAGE_B(buf, t)                                             \
  {                                                                 \
    gl2lds16(sb0 + (size_t)(t) * 32, &lds[buf][1][wave * 512 + lane * 8]);       \
    gl2lds16(sb1 + (size_t)(t) * 32, &lds[buf][1][(8 + wave) * 512 + lane * 8]); \
  }

  STAGE_A(0, 0) STAGE_B(0, 0)
  STAGE_A(1, 1) STAGE_B(1, 1)
  asm volatile("s_waitcnt vmcnt(4)" ::: "memory");
  asm volatile("s_barrier" ::: "memory");

  int buf = 0, sbuf = 2;
  for (int t = 0; t < NT; ++t) {
    const u16* As_ = &lds[buf][0][wm * (8 * 512)];
    const u16* Bs_ = &lds[buf][1][wn * (4 * 512)];

    short8 af[4], bfr[4];
    // ---- phase 1 ----
#pragma unroll
    for (int i = 0; i < 4; i++)
      af[i] = *(const short8*)(As_ + i * 512 + fo);
#pragma unroll
    for (int i = 0; i < 4; i++)
      bfr[i] = *(const short8*)(Bs_ + i * 512 + fo);
    if (t + 2 < NT) STAGE_A(sbuf, t + 2)
    asm volatile("s_barrier" ::: "memory");
    asm volatile("s_waitcnt lgkmcnt(0)" ::: "memory");
    __builtin_amdgcn_sched_barrier(0);
    __builtin_amdgcn_s_setprio(1);
#pragma unroll
    for (int mg = 0; mg < 4; mg++)
#pragma unroll
      for (int ng = 0; ng < 4; ng++)
        acc[mg][ng] = __builtin_amdgcn_mfma_f32_16x16x32_bf16(af[mg], bfr[ng],
                                                              acc[mg][ng], 0, 0, 0);
    __builtin_amdgcn_s_setprio(0);
    asm volatile("s_barrier" ::: "memory");

    // ---- phase 2 ----
#pragma unroll
    for (int i = 0; i < 4; i++)
      af[i] = *(const short8*)(As_ + (4 + i) * 512 + fo);
    if (t + 2 < NT) STAGE_B(sbuf, t + 2)
    asm volatile("s_barrier" ::: "memory");
    asm volatile("s_waitcnt lgkmcnt(0)" ::: "memory");
    __builtin_amdgcn_sched_barrier(0);
    __builtin_amdgcn_s_setprio(1);
#pragma unroll
    for (int mg = 0; mg < 4; mg++)
#pragma unroll
      for (int ng = 0; ng < 4; ng++)
        acc[4 + mg][ng] = __builtin_amdgcn_mfma_f32_16x16x32_bf16(af[mg], bfr[ng],
                                                                  acc[4 + mg][ng], 0, 0, 0);
    __builtin_amdgcn_s_setprio(0);
    if (t + 2 < NT) asm volatile("s_waitcnt vmcnt(4)" ::: "memory");
    else            asm volatile("s_waitcnt vmcnt(0)" ::: "memory");
    asm volatile("s_barrier" ::: "memory");

    buf = (buf == 2) ? 0 : buf + 1;
    sbuf = (sbuf == 2) ? 0 : sbuf + 1;
  }
#undef STAGE_A
#undef STAGE_B

  const int row0 = mBlk + wm * 128 + g * 4;
  const int col0 = nBlk + wn * 64 + l15;
#pragma unroll
  for (int ng = 0; ng < 4; ng++) {
    const int c = col0 + ng * 16;
    const float bv = bias[c];
#pragma unroll
    for (int mg = 0; mg < 8; mg++) {
#pragma unroll
      for (int r = 0; r < 4; r++) {
        float v = acc[mg][ng][r] + bv;
        if (RELU) v = fmaxf(v, 0.f);
        const size_t o = (size_t)(row0 + mg * 16 + r) * N + c;
        if (OUTBF) ((u16*)Cout)[o] = f2b(v);
        else       ((float*)Cout)[o] = v;
      }
    }
  }
}

// ---------------------------------------------------------------------------
// gemm_wide_sk: 256M x 128N tile, split-K 2, fp32 partials to
// Cout + kz*TOKENS*N (bias on kz==0). 3-deep LDS ring, one barrier/K-step,
// steady-state vmcnt(3). Quad-contiguous staging + chunk-XOR swizzle.
// ---------------------------------------------------------------------------
__global__ __launch_bounds__(512)
void gemm_wide_sk(const u16* __restrict__ A, const u16* __restrict__ Bt,
                  const float* __restrict__ bias, float* __restrict__ Cout,
                  int N, int K) {
  __shared__ __align__(16) u16 lds[3][12288];  // [buf][ A 16x512 | B 8x512 ]
  const int tid = threadIdx.x;
  const int lane = tid & 63, wave = tid >> 6;
  const int wm = wave >> 1, wn = wave & 1;  // 4M x 2N wave grid
  const int l15 = lane & 15, g = lane >> 4;

  const int bid = blockIdx.x;
  const int xcd = bid & 7, idx = bid >> 3;            // idx 0..31
  const int kz = xcd & 1;
  const int nT = ((xcd >> 1) & 1) * 4 + (idx & 3);    // 0..7
  const int mT = (xcd >> 2) * 8 + (idx >> 2);         // 0..15
  const int mBlk = mT * 256, nBlk = nT * 128;
  const int Kh = K >> 1;

  const u16* Ab = A + (size_t)mBlk * K + (size_t)kz * Kh;
  const u16* Bb = Bt + (size_t)nBlk * K + (size_t)kz * Kh;

  const int srow = lane >> 2;
  const int scolx = ((lane & 3) ^ ((lane >> 3) & 3)) * 8;
  const u16* sa0 = Ab + (size_t)(wave * 16 + srow) * K + scolx;
  const u16* sa1 = Ab + (size_t)((8 + wave) * 16 + srow) * K + scolx;
  const u16* sb0 = Bb + (size_t)(wave * 16 + srow) * K + scolx;

  const int fo = l15 * 32 + ((g ^ ((l15 >> 1) & 3)) << 3);

  f32x4 acc[4][4] = {};
  const int NT = Kh >> 5;

#define WSTAGE(buf, t)                                                         \
  {                                                                            \
    gl2lds16(sa0 + (size_t)(t) * 32, &lds[buf][wave * 512 + lane * 8]);        \
    gl2lds16(sa1 + (size_t)(t) * 32, &lds[buf][(8 + wave) * 512 + lane * 8]);  \
    gl2lds16(sb0 + (size_t)(t) * 32, &lds[buf][8192 + wave * 512 + lane * 8]); \
  }

  WSTAGE(0, 0)
  WSTAGE(1, 1)
  asm volatile("s_waitcnt vmcnt(3)" ::: "memory");
  asm volatile("s_barrier" ::: "memory");

  int buf = 0, sbuf = 2;
  for (int t = 0; t < NT; ++t) {
    const u16* As_ = &lds[buf][wm * (4 * 512)];
    const u16* Bs_ = &lds[buf][8192 + wn * (4 * 512)];
    short8 af[4], bfr[4];
#pragma unroll
    for (int i = 0; i < 4; i++)
      af[i] = *(const short8*)(As_ + i * 512 + fo);
#pragma unroll
    for (int i = 0; i < 4; i++)
      bfr[i] = *(const short8*)(Bs_ + i * 512 + fo);
    if (t + 2 < NT) WSTAGE(sbuf, t + 2)
    asm volatile("s_waitcnt lgkmcnt(0)" ::: "memory");
    __builtin_amdgcn_sched_barrier(0);
    __builtin_amdgcn_s_setprio(1);
#pragma unroll
    for (int mi = 0; mi < 4; mi++)
#pragma unroll
      for (int ni = 0; ni < 4; ni++)
        acc[mi][ni] = __builtin_amdgcn_mfma_f32_16x16x32_bf16(af[mi], bfr[ni],
                                                              acc[mi][ni], 0, 0, 0);
    __builtin_amdgcn_s_setprio(0);
    if (t + 2 < NT) asm volatile("s_waitcnt vmcnt(3)" ::: "memory");
    else            asm volatile("s_waitcnt vmcnt(0)" ::: "memory");
    asm volatile("s_barrier" ::: "memory");
    buf = (buf == 2) ? 0 : buf + 1;
    sbuf = (sbuf == 2) ? 0 : sbuf + 1;
  }
#undef WSTAGE

  float* out = Cout + (size_t)kz * TOKENS * N;
  const int row0 = mBlk + wm * 64 + g * 4;
  const int col0 = nBlk + wn * 64 + l15;
#pragma unroll
  for (int ni = 0; ni < 4; ni++) {
    const int c = col0 + ni * 16;
    const float bv = (kz == 0) ? bias[c] : 0.f;
#pragma unroll
    for (int mi = 0; mi < 4; mi++) {
#pragma unroll
      for (int r = 0; r < 4; r++)
        out[(size_t)(row0 + mi * 16 + r) * N + c] = acc[mi][ni][r] + bv;
    }
  }
}

// ---------------------------------------------------------------------------
// Fused Q+V GEMM: Bqv = [WqT | WvT] contiguous (2048 x K). Q half scaled by
// (1/sqrt(Dh)) * log2(e) -- attention uses exp2 directly.
// Quad-contiguous staging + chunk-XOR swizzle.
// ---------------------------------------------------------------------------
__global__ __launch_bounds__(256)
void gemm_qv64(const u16* __restrict__ A, const u16* __restrict__ Bqv,
               const float* __restrict__ bq, const float* __restrict__ bv,
               u16* __restrict__ qout, u16* __restrict__ vout, int K) {
  __shared__ __align__(16) u16 As[128 * 32];
  __shared__ __align__(16) u16 Bs[64 * 32];
  const int tid = threadIdx.x;
  const int lane = tid & 63, wave = tid >> 6;
  const int mBlk = blockIdx.y * 128, nBlk = blockIdx.x * 64;
  const int isQ = nBlk < 1024;
  const int ncol = isQ ? nBlk : nBlk - 1024;
  const float* bias = isQ ? bq : bv;
  u16* out = isQ ? qout : vout;
  const float oscale = isQ ? 0.125f * 1.44269504088896f : 1.0f;
  const int wm = (wave >> 1) * 64, wn = (wave & 1) * 32;
  const int l15 = lane & 15, g = lane >> 4;

  f32x4 acc[4][2] = {};
  const int srow = lane >> 2;
  const int scolx = ((lane & 3) ^ ((lane >> 3) & 3)) * 8;
  const int fo = l15 * 32 + ((g ^ ((l15 >> 1) & 3)) << 3);

  const u16* Ab = A + (size_t)mBlk * K;
  const u16* Bb = Bqv + (size_t)nBlk * K;

  for (int k0 = 0; k0 < K; k0 += 32) {
    __syncthreads();
    for (int c = wave; c < 8; c += 4)
      gl2lds16(Ab + (size_t)(c * 16 + srow) * K + k0 + scolx, As + c * 512 + lane * 8);
    gl2lds16(Bb + (size_t)(wave * 16 + srow) * K + k0 + scolx, Bs + wave * 512 + lane * 8);
    __syncthreads();

    short8 af[4], bf[2];
#pragma unroll
    for (int i = 0; i < 4; i++)
      af[i] = *(const short8*)(As + ((wm >> 4) + i) * 512 + fo);
#pragma unroll
    for (int i = 0; i < 2; i++)
      bf[i] = *(const short8*)(Bs + ((wn >> 4) + i) * 512 + fo);
#pragma unroll
    for (int mi = 0; mi < 4; mi++)
#pragma unroll
      for (int ni = 0; ni < 2; ni++)
        acc[mi][ni] = __builtin_amdgcn_mfma_f32_16x16x32_bf16(af[mi], bf[ni],
                                                              acc[mi][ni], 0, 0, 0);
  }

  const int row0 = mBlk + wm + g * 4;
  const int col0 = ncol + wn + l15;
#pragma unroll
  for (int ni = 0; ni < 2; ni++) {
    const int c = col0 + ni * 16;
    const float bv_ = bias[c];
#pragma unroll
    for (int mi = 0; mi < 4; mi++) {
#pragma unroll
      for (int r = 0; r < 4; r++) {
        float v = (acc[mi][ni][r] + bv_) * oscale;
        out[(size_t)(row0 + mi * 16 + r) * E_DIM + c] = f2b(v);
      }
    }
  }
}

// ---------------------------------------------------------------------------
// Flash attention v6: hoisted-address + compile-time double-buffer restructure.
// Same math/staging/barrier schedule as v5; the kc loop is unrolled by 2 so
// the buffer index is compile-time (even tile -> buf0, odd -> buf1), and all
// LDS addresses are decomposed into 10 hoisted per-lane base pointers +
// compile-time immediates:
//   key&7 == l15&7 and d&7 == l15&7 (16 = 0 mod 8), so
//   QK b0/b1:  base(l15,g) + nt*1024 u16   (2 bases; buf1 = +4096)
//   PV bv0/1:  base(l15,g) + dt*1024 u16   (2 bases; buf1 = +4096)
//   PV ap0/1, pack wr0..wr3: fully loop-invariant (6 bases)
// v5 recomputed these XOR chains per tile (VALUBusy 47%, 52 VGPR -> issue-
// bound on address math); v6 trades ~40 VGPRs for ~half the VALU traffic.
// ---------------------------------------------------------------------------
__global__ __launch_bounds__(256)
void attn_kernel(const u16* __restrict__ qb, const u16* __restrict__ vb,
                 const u16* __restrict__ vtb, u16* __restrict__ ctxb) {
  __shared__ __align__(16) u16 Vs[2][4096];   // [key][d-chunk ^ (key&7)]
  __shared__ __align__(16) u16 Vts[2][4096];  // [d][pos-chunk ^ (d&7)]
  __shared__ __align__(16) u16 Pl[4][1024];   // per-wave P, XOR swizzled
  const int tid = threadIdx.x;
  const int lane = tid & 63;
  const int wave = tid >> 6;
  const int l15 = lane & 15;
  const int g = lane >> 4;
  const int l7 = l15 & 7;
  const int qblk = blockIdx.x;
  const int bh = blockIdx.y;
  const int b = bh >> 4;
  const int h = bh & 15;
  const int qrow = qblk * 64 + wave * 16;

  short8 aq0, aq1;
  {
    const u16* qp = qb + ((size_t)(b * SEQ + qrow + l15)) * E_DIM + h * DH + g * 8;
    aq0 = *(const short8*)(qp);
    aq1 = *(const short8*)(qp + 32);
  }

  f32x4 o[4] = {};
  float lsum[4] = {};

  u16* myPl = Pl[wave];

  // hoisted LDS base pointers (buf0; buf1 = +4096 for Vs/Vts)
  const u16* qk0b0 = Vs[0] + l15 * 64 + ((g ^ l7) * 8);
  const u16* qk1b0 = Vs[0] + l15 * 64 + (((4 + g) ^ l7) * 8);
  const u16* bv0b0 = Vts[0] + l15 * 64 + ((g ^ l7) * 8);
  const u16* bv1b0 = Vts[0] + l15 * 64 + (((4 + g) ^ l7) * 8);
  const u16* ap0 = myPl + l15 * 64 + ((g ^ l7) << 3);
  const u16* ap1 = myPl + l15 * 64 + (((4 + g) ^ l7) << 3);
  u16* wr0 = myPl + (g * 4 + 0) * 64 + (((l15 >> 1) ^ ((g * 4 + 0) & 7)) << 3) + ((l15 & 1) << 2);
  u16* wr1 = myPl + (g * 4 + 1) * 64 + (((l15 >> 1) ^ ((g * 4 + 1) & 7)) << 3) + ((l15 & 1) << 2);
  u16* wr2 = myPl + (g * 4 + 2) * 64 + (((l15 >> 1) ^ ((g * 4 + 2) & 7)) << 3) + ((l15 & 1) << 2);
  u16* wr3 = myPl + (g * 4 + 3) * 64 + (((l15 >> 1) ^ ((g * 4 + 3) & 7)) << 3) + ((l15 & 1) << 2);

  // staging pointers (advance by one 64-key window per STAGE)
  const int srow = tid >> 3;  // 0..31
  const int sch = tid & 7;    // 0..7 (16B chunk)
  const int r0 = srow, r1 = 32 + srow;
  const u16* pv0 = vb + ((size_t)(b * SEQ) + r0) * E_DIM + h * DH + ((sch ^ (r0 & 7)) * 8);
  const u16* pv1 = vb + ((size_t)(b * SEQ) + r1) * E_DIM + h * DH + ((sch ^ (r1 & 7)) * 8);
  const u16* pt0 = vtb + ((size_t)bh * DH + r0) * SEQ + ((sch ^ (r0 & 7)) * 8);
  const u16* pt1 = vtb + ((size_t)bh * DH + r1) * SEQ + ((sch ^ (r1 & 7)) * 8);

#define STAGE(buf)                                      \
  {                                                     \
    gl2lds16(pv0, Vs[buf] + tid * 8);                   \
    gl2lds16(pv1, Vs[buf] + 2048 + tid * 8);            \
    gl2lds16(pt0, Vts[buf] + tid * 8);                  \
    gl2lds16(pt1, Vts[buf] + 2048 + tid * 8);           \
    pv0 += 64 * E_DIM; pv1 += 64 * E_DIM;               \
    pt0 += 64; pt1 += 64;                               \
  }

#define SMROW(r, WR)                                                          \
  {                                                                           \
    union { float f; unsigned u; } p0, p1, p2, p3;                            \
    p0.f = __builtin_amdgcn_exp2f(s[0][r]);                                   \
    p1.f = __builtin_amdgcn_exp2f(s[1][r]);                                   \
    p2.f = __builtin_amdgcn_exp2f(s[2][r]);                                   \
    p3.f = __builtin_amdgcn_exp2f(s[3][r]);                                   \
    union { unsigned u; float f; } t0, t1, t2, t3;                            \
    t0.u = p0.u & 0xffff0000u; t1.u = p1.u & 0xffff0000u;                     \
    t2.u = p2.u & 0xffff0000u; t3.u = p3.u & 0xffff0000u;                     \
    lsum[r] += (t0.f + t1.f) + (t2.f + t3.f);                                 \
    uint2 pk;                                                                 \
    pk.x = __builtin_amdgcn_perm(p1.u, p0.u, 0x07060302u);                    \
    pk.y = __builtin_amdgcn_perm(p3.u, p2.u, 0x07060302u);                    \
    *(uint2*)(WR) = pk;                                                       \
  }

#define COMPUTE(QK0, QK1, BV0, BV1)                                           \
  {                                                                           \
    f32x4 s[4];                                                               \
    _Pragma("unroll") for (int nt = 0; nt < 4; nt++) {                        \
      short8 b0 = *(const short8*)((QK0) + nt * 1024);                        \
      short8 b1 = *(const short8*)((QK1) + nt * 1024);                        \
      f32x4 z = {};                                                           \
      z = __builtin_amdgcn_mfma_f32_16x16x32_bf16(aq0, b0, z, 0, 0, 0);       \
      z = __builtin_amdgcn_mfma_f32_16x16x32_bf16(aq1, b1, z, 0, 0, 0);       \
      s[nt] = z;                                                              \
    }                                                                         \
    SMROW(0, wr0) SMROW(1, wr1) SMROW(2, wr2) SMROW(3, wr3)                   \
    {                                                                         \
      short8 ap = *(const short8*)ap0;                                        \
      _Pragma("unroll") for (int dt = 0; dt < 4; dt++) {                      \
        short8 bvv = *(const short8*)((BV0) + dt * 1024);                     \
        o[dt] = __builtin_amdgcn_mfma_f32_16x16x32_bf16(ap, bvv, o[dt], 0, 0, 0); \
      }                                                                       \
      ap = *(const short8*)ap1;                                               \
      _Pragma("unroll") for (int dt = 0; dt < 4; dt++) {                      \
        short8 bvv = *(const short8*)((BV1) + dt * 1024);                     \
        o[dt] = __builtin_amdgcn_mfma_f32_16x16x32_bf16(ap, bvv, o[dt], 0, 0, 0); \
      }                                                                       \
    }                                                                         \
  }

  // HALF(CB, EN): barrier A (readers of target buf done) -> stage next tile
  // into buf CB^1 -> vmcnt(4): my 4 older loads (into buf CB) are done ->
  // barrier B -> compute buf CB. Same race argument as v4/v5.
#define HALF(CB, EN)                                                          \
  {                                                                           \
    asm volatile("s_barrier" ::: "memory");                                   \
    if (EN) {                                                                 \
      STAGE(CB ^ 1)                                                           \
      asm volatile("s_waitcnt vmcnt(4)" ::: "memory");                        \
    } else {                                                                  \
      asm volatile("s_waitcnt vmcnt(0)" ::: "memory");                        \
    }                                                                         \
    asm volatile("s_barrier" ::: "memory");                                   \
    if (CB == 0) { COMPUTE(qk0b0, qk1b0, bv0b0, bv1b0) }                      \
    else { COMPUTE(qk0b0 + 4096, qk1b0 + 4096, bv0b0 + 4096, bv1b0 + 4096) }  \
  }

  STAGE(0)  // tile 0 -> buf0
#pragma unroll 1
  for (int it = 0; it < 15; ++it) {
    HALF(0, 1)  // compute tile 2it   (buf0), stage tile 2it+1 -> buf1
    HALF(1, 1)  // compute tile 2it+1 (buf1), stage tile 2it+2 -> buf0
  }
  HALF(0, 1)  // compute tile 30 (buf0), stage tile 31 -> buf1
  HALF(1, 0)  // compute tile 31 (buf1), drain

#undef HALF
#undef COMPUTE
#undef SMROW
#undef STAGE

#pragma unroll
  for (int r = 0; r < 4; r++) {
    float l = lsum[r];
    l += __shfl_xor(l, 1);
    l += __shfl_xor(l, 2);
    l += __shfl_xor(l, 4);
    l += __shfl_xor(l, 8);
    const float inv = 1.0f / l;
    size_t base = ((size_t)(b * SEQ + qrow + g * 4 + r)) * E_DIM + h * DH;
#pragma unroll
    for (int dt = 0; dt < 4; dt++)
      ctxb[base + dt * 16 + l15] = f2b(o[dt][r] * inv);
  }
}

// ---------------------------------------------------------------------------
// out = LayerNorm(X + Y0 + Y1); Y0/Y1 = split-K partials. In-place safe when
// out32 aliases an input (each thread reads its own row elements first).
// ---------------------------------------------------------------------------
__global__ __launch_bounds__(256)
void add_ln3(const float* __restrict__ X, const float* __restrict__ Y0,
             const float* __restrict__ Y1,
             const float* __restrict__ gam, const float* __restrict__ bet,
             float* __restrict__ out32, u16* __restrict__ out16) {
  const int row = blockIdx.x;
  const int tid = threadIdx.x;
  const size_t base = (size_t)row * E_DIM;
  float v[4];
  float s = 0.f, sq = 0.f;
#pragma unroll
  for (int i = 0; i < 4; i++) {
    const int c = tid + i * 256;
    float x = X[base + c] + Y0[base + c] + Y1[base + c];
    v[i] = x; s += x; sq += x * x;
  }
#pragma unroll
  for (int off = 32; off; off >>= 1) {
    s += __shfl_xor(s, off);
    sq += __shfl_xor(sq, off);
  }
  __shared__ float sh[8];
  const int wave = tid >> 6, lane = tid & 63;
  if (lane == 0) { sh[wave] = s; sh[4 + wave] = sq; }
  __syncthreads();
  s = sh[0] + sh[1] + sh[2] + sh[3];
  sq = sh[4] + sh[5] + sh[6] + sh[7];
  const float mean = s * (1.f / 1024.f);
  const float var = sq * (1.f / 1024.f) - mean * mean;
  const float rstd = rsqrtf(var + 1e-5f);
#pragma unroll
  for (int i = 0; i < 4; i++) {
    const int c = tid + i * 256;
    float y = (v[i] - mean) * rstd * gam[c] + bet[c];
    out32[base + c] = y;
    if (out16) out16[base + c] = f2b(y);
  }
}

// ---------------------------------------------------------------------------
extern "C" void kernel_launch(void* const* d_in, const int* in_sizes, int n_in,
                              void* d_out, int out_size, void* d_ws, size_t ws_size,
                              hipStream_t stream) {
  const float* x   = (const float*)d_in[0];
  const float* Wq  = (const float*)d_in[1];
  const float* bq  = (const float*)d_in[2];
  // d_in[3]=Wk, d_in[4]=bk -- dead code in the reference (scores use Q@V^T)
  const float* Wv  = (const float*)d_in[5];
  const float* bv  = (const float*)d_in[6];
  const float* Wo  = (const float*)d_in[7];
  const float* bo  = (const float*)d_in[8];
  const float* g1  = (const float*)d_in[9];
  const float* b1  = (const float*)d_in[10];
  const float* W1  = (const float*)d_in[11];
  const float* bf1 = (const float*)d_in[12];
  const float* W2  = (const float*)d_in[13];
  const float* bf2 = (const float*)d_in[14];
  const float* g2  = (const float*)d_in[15];
  const float* b2  = (const float*)d_in[16];

  char* w = (char*)d_ws;
  const size_t MB = 1024ull * 1024ull;
  u16*   xb   = (u16*)(w + 0);          //  8MB
  u16*   h1   = (u16*)(w + 8 * MB);     // 32MB
  u16*   qb   = (u16*)(w + 8 * MB);     //  8MB
  u16*   vb   = (u16*)(w + 16 * MB);    //  8MB
  u16*   vtb  = (u16*)(w + 24 * MB);    //  8MB
  u16*   ctxb = (u16*)(w + 32 * MB);    //  8MB
  float* att0 = (float*)(w + 40 * MB);  // 32MB (both Wo partials, contiguous)
  float* ff0  = (float*)(w + 40 * MB);  // 32MB (both FF2 partials, contiguous)
  float* pa   = (float*)(w + 72 * MB);  // 16MB
  u16*   pab  = (u16*)(w + 88 * MB);    //  8MB
  u16*   WqT  = (u16*)(w + 96 * MB);    //  2MB (WqT|WvT contiguous)
  u16*   WvT  = (u16*)(w + 98 * MB);    //  2MB
  u16*   WoT  = (u16*)(w + 100 * MB);   //  2MB
  u16*   W1T  = (u16*)(w + 102 * MB);   //  8MB
  u16*   W2T  = (u16*)(w + 110 * MB);   //  8MB -> 118MB total

  transpose_w<<<dim3(32, 32), 256, 0, stream>>>(Wq, WqT, 1024, 1024);
  transpose_w<<<dim3(32, 32), 256, 0, stream>>>(Wv, WvT, 1024, 1024);
  transpose_w<<<dim3(32, 32), 256, 0, stream>>>(Wo, WoT, 1024, 1024);
  transpose_w<<<dim3(32, 128), 256, 0, stream>>>(W1, W1T, 1024, 4096);
  transpose_w<<<dim3(128, 32), 256, 0, stream>>>(W2, W2T, 4096, 1024);
  f32_to_bf16<<<TOKENS * E_DIM / 4 / 256, 256, 0, stream>>>(x, xb);

  gemm_qv64<<<dim3(32, 32), 256, 0, stream>>>(xb, WqT, bq, bv, qb, vb, 1024);
  transpose_v<<<dim3(32, 32), 256, 0, stream>>>(vb, vtb);
  attn_kernel<<<dim3(32, 32), 256, 0, stream>>>(qb, vb, vtb, ctxb);
  gemm_wide_sk<<<dim3(256), 512, 0, stream>>>(ctxb, WoT, bo, att0, 1024, 1024);
  add_ln3<<<TOKENS, 256, 0, stream>>>(x, att0, att0 + (size_t)TOKENS * 1024, g1, b1, pa, pab);
  gemm256<1, 1><<<dim3(256), 512, 0, stream>>>(pab, W1T, bf1, h1, 4096, 1024);
  gemm_wide_sk<<<dim3(256), 512, 0, stream>>>(h1, W2T, bf2, ff0, 1024, 4096);
  add_ln3<<<TOKENS, 256, 0, stream>>>(pa, ff0, ff0 + (size_t)TOKENS * 1024, g2, b2, (float*)d_out, (u16*)nullptr);
}